// Round 16
// baseline (1696.284 us; speedup 1.0000x reference)
//
#include <hip/hip_runtime.h>
#include <cstdint>
#include <cmath>

#define DEVINL __device__ __forceinline__

struct U2 { uint32_t a, b; };
typedef float v2f __attribute__((ext_vector_type(2)));

DEVINL uint32_t rotl32(uint32_t x, uint32_t r){ return (x << r) | (x >> (32u - r)); }

// Threefry-2x32, 20 rounds (Random123 / JAX-compatible)
DEVINL U2 tf(uint32_t k0, uint32_t k1, uint32_t x0, uint32_t x1){
  const uint32_t k2 = k0 ^ k1 ^ 0x1BD11BDAu;
  x0 += k0; x1 += k1;
#define TFR(r) { x0 += x1; x1 = rotl32(x1,(r)); x1 ^= x0; }
  TFR(13) TFR(15) TFR(26) TFR(6)  x0 += k1; x1 += k2 + 1u;
  TFR(17) TFR(29) TFR(16) TFR(24) x0 += k2; x1 += k0 + 2u;
  TFR(13) TFR(15) TFR(26) TFR(6)  x0 += k0; x1 += k1 + 3u;
  TFR(17) TFR(29) TFR(16) TFR(24) x0 += k1; x1 += k2 + 4u;
  TFR(13) TFR(15) TFR(26) TFR(6)  x0 += k2; x1 += k0 + 5u;
#undef TFR
  U2 r; r.a = x0; r.b = x1; return r;
}

// partitionable random_bits (32-bit): one tf per element, XOR both words
DEVINL uint32_t pbits(uint32_t k0, uint32_t k1, uint32_t idx){
  U2 r = tf(k0, k1, 0u, idx);
  return r.a ^ r.b;
}

// JAX uniform bits -> [0,1): bitcast((bits>>9)|0x3F800000) - 1
DEVINL float u01(uint32_t bits){
  return __uint_as_float((bits >> 9) | 0x3F800000u) - 1.0f;
}

// XLA:CPU vectorized log (Cephes), FMA-contracted Horner
DEVINL float xla_logf(float xin){
  float xf = fmaxf(__uint_as_float(0x00800000u), xin);   // flush denorm/zero up
  uint32_t ib = __float_as_uint(xf);
  float e = (float)((int)(ib >> 23) - 126);
  float x = __uint_as_float((ib & 0x807fffffu) | 0x3f000000u);  // [0.5,1)
  bool m = x < 0.707106781186547524f;
  float t = m ? x : 0.0f;
  x = __fsub_rn(x, 1.0f);
  if (m) e = __fsub_rn(e, 1.0f);
  x = __fadd_rn(x, t);
  float z = __fmul_rn(x, x);
  float y = 7.0376836292e-2f;
  y = fmaf(y, x, -1.1514610310e-1f);
  y = fmaf(y, x,  1.1676998740e-1f);
  y = fmaf(y, x, -1.2420140846e-1f);
  y = fmaf(y, x,  1.4249322787e-1f);
  y = fmaf(y, x, -1.6668057665e-1f);
  y = fmaf(y, x,  2.0000714765e-1f);
  y = fmaf(y, x, -2.4999993993e-1f);
  y = fmaf(y, x,  3.3333331174e-1f);
  y = __fmul_rn(y, x);
  y = __fmul_rn(y, z);
  y = fmaf(e, -2.12194440e-4f, y);
  y = fmaf(z, -0.5f, y);
  x = __fadd_rn(x, y);
  x = fmaf(e, 0.693359375f, x);
  if (xin == 0.0f) x = __uint_as_float(0xff800000u);  // -inf
  return x;
}

// XLA EmitLog1p: |x|<1e-4 -> x*(1 + (-0.5)*x), else log(1+x)
DEVINL float xla_log1pf(float v){
  float av = fabsf(v);
  if (av < 1e-4f) return __fmul_rn(__fadd_rn(__fmul_rn(-0.5f, v), 1.0f), v);
  return xla_logf(__fadd_rn(v, 1.0f));
}

// XLA ErfInv32 (Giles), strict mul/add
DEVINL float erfinv32(float x){
  float xx = __fmul_rn(x, x);
  float w = -xla_log1pf(-xx);
  float p;
  if (w < 5.0f){
    float ww = __fsub_rn(w, 2.5f);
    p = 2.81022636e-08f;
    p = __fadd_rn( 3.43273939e-07f, __fmul_rn(p, ww));
    p = __fadd_rn(-3.5233877e-06f,  __fmul_rn(p, ww));
    p = __fadd_rn(-4.39150654e-06f, __fmul_rn(p, ww));
    p = __fadd_rn( 0.00021858087f,  __fmul_rn(p, ww));
    p = __fadd_rn(-0.00125372503f,  __fmul_rn(p, ww));
    p = __fadd_rn(-0.00417768164f,  __fmul_rn(p, ww));
    p = __fadd_rn( 0.246640727f,    __fmul_rn(p, ww));
    p = __fadd_rn( 1.50140941f,     __fmul_rn(p, ww));
  } else {
    float ww = __fsub_rn(sqrtf(w), 3.0f);
    p = -0.000200214257f;
    p = __fadd_rn( 0.000100950558f, __fmul_rn(p, ww));
    p = __fadd_rn( 0.00134934322f,  __fmul_rn(p, ww));
    p = __fadd_rn(-0.00367342844f,  __fmul_rn(p, ww));
    p = __fadd_rn( 0.00573950773f,  __fmul_rn(p, ww));
    p = __fadd_rn(-0.0076224613f,   __fmul_rn(p, ww));
    p = __fadd_rn( 0.00943887047f,  __fmul_rn(p, ww));
    p = __fadd_rn( 1.00167406f,     __fmul_rn(p, ww));
    p = __fadd_rn( 2.83297682f,     __fmul_rn(p, ww));
  }
  return __fmul_rn(p, x);
}

#define SQRT2F (__uint_as_float(0x3FB504F3u))   /* f32(sqrt(2)) */
#define NLOF   (__uint_as_float(0xBF7FFFFFu))   /* nextafterf(-1,0) */
#define SQDTF  ((float)0.14142135623730951)     /* f32(sqrt(0.02)) */

DEVINL float normal_from_bits(uint32_t bits){
  float ff = u01(bits);
  float u = __fadd_rn(__fmul_rn(ff, 2.0f), NLOF);
  u = fmaxf(NLOF, u);
  return __fmul_rn(SQRT2F, erfinv32(u));
}

// fast tanh for the smooth drift path (no PRNG decision depends on it)
DEVINL float fast_tanh(float x){
  float ax = fabsf(x);
  float e = __expf(-2.0f * ax);
  float r = (1.0f - e) * __builtin_amdgcn_rcpf(1.0f + e);
  return __builtin_copysignf(r, x);
}

// packed 2xf32 fma (v_pk_fma_f32 on gfx950); per-component IEEE fma
DEVINL v2f f2fma(v2f a, v2f b, v2f c){ return __builtin_elementwise_fma(a, b, c); }

// One rejection-sampling ATTEMPT (incl. inner v>0 loop). Returns accept;
// decision/value sequence byte-identical to one iteration of jax _gamma_one.
DEVINL bool gamma_attempt(uint32_t K0, uint32_t K1, float d, float c, float& out){
  U2 xk = tf(K0, K1, 0u, 1u);
  U2 Uk = tf(K0, K1, 0u, 2u);
  float xx, v;
  for (;;) {
    U2 sub = tf(xk.a, xk.b, 0u, 1u);
    xx = normal_from_bits(pbits(sub.a, sub.b, 0u));
    v = __fadd_rn(1.0f, __fmul_rn(xx, c));
    if (v > 0.0f) break;
    xk = tf(xk.a, xk.b, 0u, 0u);
  }
  float X = __fmul_rn(xx, xx);
  float V = __fmul_rn(__fmul_rn(v, v), v);
  float U = u01(pbits(Uk.a, Uk.b, 0u));
  float sq = __fsub_rn(1.0f, __fmul_rn(0.0331f, __fmul_rn(X, X)));
  if (U < sq) { out = __fmul_rn(d, V); return true; }
  float lnU = xla_logf(U);
  float lnV = xla_logf(V);
  float rhs = __fadd_rn(__fmul_rn(X, 0.5f),
                        __fmul_rn(d, __fadd_rn(__fsub_rn(1.0f, V), lnV)));
  if (lnU < rhs) { out = __fmul_rn(d, V); return true; }
  return false;
}

// Full loop starting from a given chain key K (used by retry, K pre-advanced).
DEVINL float gamma_fromK(uint32_t K0, uint32_t K1, float alpha){
  const float d = __fsub_rn(alpha, (1.0f/3.0f));
  const float c = (1.0f/3.0f) / sqrtf(d);
  for (;;) {
    float s;
    if (gamma_attempt(K0, K1, d, c, s)) return s;
    U2 K = tf(K0, K1, 0u, 0u);
    K0 = K.a; K1 = K.b;
  }
}

// jax _gamma_one from the per-element key (tier-1/fallback use).
DEVINL float gamma_one(uint32_t gk0, uint32_t gk1, float alpha){
  U2 K = tf(gk0, gk1, 0u, 0u);   // key,subkey=split; u_boost unused for alpha>=1
  return gamma_fromK(K.a, K.b, alpha);
}

#define NPK 24
#define WSTRIDE (4 + 2*NPK)
#define KEYOFF 8
#define JOFF   16384
#define RSLOT 128          /* retry records per pois block (mean 49, 12-sigma) */

// Per-step keys: kn, kg, Poisson subkey chain.
__global__ void setup_kernel(uint32_t* __restrict__ ws, int steps){
  int t = blockIdx.x * blockDim.x + threadIdx.x;
  if (t >= steps) return;
  U2 kt = tf(0u, 42u, 0u, (uint32_t)t);
  U2 kp = tf(kt.a, kt.b, 0u, 0u);
  U2 kn = tf(kt.a, kt.b, 0u, 1u);
  U2 kg = tf(kt.a, kt.b, 0u, 2u);
  uint32_t* p = ws + KEYOFF + (size_t)t * WSTRIDE;
  p[0] = kn.a; p[1] = kn.b;
  p[2] = kg.a; p[3] = kg.b;
  uint32_t r0 = kp.a, r1 = kp.b;
  for (int i = 0; i < NPK; ++i) {
    U2 sub = tf(r0, r1, 0u, 1u);
    U2 rn  = tf(r0, r1, 0u, 0u);
    p[4 + 2*i] = sub.a; p[5 + 2*i] = sub.b;
    r0 = rn.a; r1 = rn.b;
  }
}

// ---- Phase A1: Poisson first TWO draws (81% finish), straight-line uniform.
// Noise terms into jarr; pois byte 0/1 (or placeholder for retries); retry
// records (t,e,lp2) into per-block region of the worklist area; counts packed
// gamma | retry<<16 into COFF.
__global__ __launch_bounds__(256) void pois1_kernel(
    uint32_t* __restrict__ ws, const float* __restrict__ diffp,
    int N, int steps, uint32_t POFF, uint32_t COFF, uint32_t WOFF)
{
  __shared__ uint32_t gcnts[4], rcnts[4];
  int e = blockIdx.x * 256 + threadIdx.x;
  int t = blockIdx.y;
  bool act = e < N;
  const uint32_t* __restrict__ p = ws + KEYOFF + (size_t)t * WSTRIDE;
  const float coef = __fmul_rn(diffp[0], SQDTF);

  bool g = false, retry = false;
  float lp2 = 0.0f;
  int pois01 = 0;
  if (act) {
    const uint32_t ue = (uint32_t)e;
    // draws 1 & 2 unconditionally (element-indexed streams; unused = discarded)
    float l1 = xla_logf(u01(pbits(p[4], p[5], ue)));
    float l2 = xla_logf(u01(pbits(p[6], p[7], ue)));
    float lpa = __fadd_rn(0.0f, l1);
    g = (lpa > -0.8f);                     // pois >= 1
    lp2 = __fadd_rn(lpa, l2);
    retry = g && (lp2 > -0.8f);            // pois >= 2
    pois01 = g ? 1 : 0;
    // noise terms
    float nf0 = normal_from_bits(pbits(p[0], p[1], 2u*ue));
    float nf1 = normal_from_bits(pbits(p[0], p[1], 2u*ue + 1u));
    float* jarr = (float*)(ws + JOFF);
    size_t jb = (size_t)t * (size_t)(2*N) + 2u*ue;
    jarr[jb]     = __fmul_rn(coef, nf0);
    jarr[jb + 1] = __fmul_rn(coef, nf1);
    ((uint8_t*)ws)[(size_t)POFF*4u + (size_t)t*(size_t)N + (size_t)e] =
        (uint8_t)pois01;                   // retries overwritten by retry pass
  }

  uint64_t gb = __ballot(g);
  uint64_t rb = __ballot(retry);
  int lane = threadIdx.x & 63, w = threadIdx.x >> 6;
  if (lane == 0) { gcnts[w] = (uint32_t)__popcll(gb); rcnts[w] = (uint32_t)__popcll(rb); }
  __syncthreads();
  uint32_t bid = (uint32_t)blockIdx.y * gridDim.x + blockIdx.x;
  // rank-scatter retry records into block-private region
  if (retry) {
    uint32_t base = 0;
    for (int w2 = 0; w2 < w; ++w2) base += rcnts[w2];
    uint32_t rank = base + (uint32_t)__popcll(rb & ((1ull << lane) - 1ull));
    if (rank < RSLOT) {
      uint32_t* rec = ws + WOFF + (size_t)bid * (2u*RSLOT) + 2u*rank;
      rec[0] = ((uint32_t)t << 23) | ((uint32_t)e << 6);
      rec[1] = __float_as_uint(lp2);
    }
  }
  if (threadIdx.x == 0) {
    uint32_t gc = gcnts[0] + gcnts[1] + gcnts[2] + gcnts[3];
    uint32_t rc = rcnts[0] + rcnts[1] + rcnts[2] + rcnts[3];
    ws[COFF + bid] = gc | (rc << 16);
  }
}

// ---- Phase A2: continue Knuth chains for pois>=2 elements (19%).
__global__ __launch_bounds__(64) void pois_retry_kernel(
    uint32_t* __restrict__ ws, int N, uint32_t POFF, uint32_t COFF, uint32_t WOFF)
{
  uint32_t bid = (uint32_t)blockIdx.y * gridDim.x + blockIdx.x;
  uint32_t cnt = ws[COFF + bid] >> 16;
  if (cnt > RSLOT) cnt = RSLOT;
  const int t = blockIdx.y;
  const uint32_t* __restrict__ p = ws + KEYOFF + (size_t)t * WSTRIDE;
  uint8_t* pb = (uint8_t*)ws + (size_t)POFF * 4u + (size_t)t * (size_t)N;
  const uint32_t* base = ws + WOFF + (size_t)bid * (2u*RSLOT);
  for (uint32_t r = threadIdx.x; r < cnt; r += 64) {
    uint32_t rec0 = base[2*r];
    float lp = __uint_as_float(base[2*r + 1]);
    uint32_t e = (rec0 >> 6) & 0x1FFFFu;
    int k = 2;
    #pragma unroll 1
    while (lp > -0.8f && k < NPK) {
      uint32_t bits = pbits(p[4 + 2*k], p[5 + 2*k], e);
      lp = __fadd_rn(lp, xla_logf(u01(bits)));
      k++;
    }
    int pois = (lp > -0.8f) ? (NPK - 1) : (k - 1);
    pb[e] = (uint8_t)pois;
  }
}

// ---- prefix over NB block counts (optionally masking low 16 bits);
// total -> ws[outIdx].
__global__ __launch_bounds__(256) void prefix_kernel(
    uint32_t* __restrict__ ws, uint32_t COFF, uint32_t BOFF, int NB,
    int outIdx, int mask16)
{
  __shared__ uint32_t ssum[256];
  int i = threadIdx.x;
  int chunk = (NB + 255) >> 8;
  int lo = i * chunk, hi = lo + chunk; if (hi > NB) hi = NB;
  uint32_t s = 0;
  for (int j = lo; j < hi; ++j) {
    uint32_t v = ws[COFF + j];
    s += mask16 ? (v & 0xFFFFu) : v;
  }
  ssum[i] = s;
  __syncthreads();
  if (i == 0) {
    uint32_t run = 0;
    for (int k = 0; k < 256; ++k) { uint32_t c = ssum[k]; ssum[k] = run; run += c; }
    ws[outIdx] = run;
  }
  __syncthreads();
  uint32_t base = ssum[i];
  for (int j = lo; j < hi; ++j) {
    ws[BOFF + j] = base;
    uint32_t v = ws[COFF + j];
    base += mask16 ? (v & 0xFFFFu) : v;
  }
}

// ---- Phase S: deterministic rank-scatter of (t,e,pois) entries.
__global__ __launch_bounds__(256) void scatter_kernel(
    uint32_t* __restrict__ ws, int N, int steps,
    uint32_t POFF, uint32_t BOFF, uint32_t WOFF, uint32_t CAP)
{
  __shared__ uint32_t cnts[4];
  int e = blockIdx.x * 256 + threadIdx.x;
  int t = blockIdx.y;
  bool act = e < N;
  uint32_t pv = 0;
  if (act) pv = ((const uint8_t*)ws)[(size_t)POFF*4u + (size_t)t*(size_t)N + (size_t)e];
  uint64_t b = __ballot(pv > 0);
  int lane = threadIdx.x & 63, w = threadIdx.x >> 6;
  if (lane == 0) cnts[w] = (uint32_t)__popcll(b);
  __syncthreads();
  uint32_t bid = (uint32_t)blockIdx.y * gridDim.x + blockIdx.x;
  uint32_t wb = ws[BOFF + bid];
  for (int w2 = 0; w2 < w; ++w2) wb += cnts[w2];
  if (pv > 0) {
    uint32_t rank = (uint32_t)__popcll(b & ((1ull << lane) - 1ull));
    uint32_t idx = wb + rank;
    if (idx < CAP)
      ws[WOFF + idx] = ((uint32_t)t << 23) | ((uint32_t)e << 6) | pv;
  }
}

// ---- Phase G1: FIRST ATTEMPT only per gamma (96% accept, no outer replay).
__global__ __launch_bounds__(256) void gamma_pass1(
    uint32_t* __restrict__ ws, int N,
    uint32_t WOFF, uint32_t CAP, uint32_t FOFF, uint32_t COFF)
{
  __shared__ uint32_t cnts[4];
  uint32_t total = ws[0]; if (total > CAP) total = CAP;
  uint32_t j = blockIdx.x * 256u + threadIdx.x;
  uint32_t fb = 0;
  if (j < total) {
    uint32_t ent = ws[WOFF + j];
    uint32_t t = ent >> 23, e = (ent >> 6) & 0x1FFFFu, pv = ent & 0x3Fu;
    const uint32_t* __restrict__ p = ws + KEYOFF + (size_t)t * WSTRIDE;
    uint32_t kg0 = p[2], kg1 = p[3];
    float alpha = (float)pv;
    const float d = __fsub_rn(alpha, (1.0f/3.0f));
    const float c = (1.0f/3.0f) / sqrtf(d);
    float add0 = 0.0f, add1 = 0.0f;
    {
      U2 gk = tf(kg0, kg1, 0u, 2u*e);
      U2 K  = tf(gk.a, gk.b, 0u, 0u);
      float s;
      if (gamma_attempt(K.a, K.b, d, c, s)) add0 = s / 10.0f; else fb |= 1u;
    }
    {
      U2 gk = tf(kg0, kg1, 0u, 2u*e + 1u);
      U2 K  = tf(gk.a, gk.b, 0u, 0u);
      float s;
      if (gamma_attempt(K.a, K.b, d, c, s)) add1 = s; else fb |= 2u;
    }
    float* jarr = (float*)(ws + JOFF);
    float2* slot = (float2*)&jarr[(size_t)t * (size_t)(2*N) + (size_t)(2u*e)];
    float2 v = *slot;
    v.x = __fadd_rn(v.x, add0);
    v.y = __fadd_rn(v.y, add1);
    *slot = v;
  }
  if (j < CAP) ((uint8_t*)ws)[(size_t)FOFF*4u + j] = (uint8_t)fb;
  uint64_t b = __ballot(fb != 0u);
  int lane = threadIdx.x & 63, w = threadIdx.x >> 6;
  if (lane == 0) cnts[w] = (uint32_t)__popcll(b);
  __syncthreads();
  if (threadIdx.x == 0)
    ws[COFF + blockIdx.x] = cnts[0] + cnts[1] + cnts[2] + cnts[3];
}

// ---- Phase G2: rank-scatter failed entries (packed (j<<2)|fb) into the
// spare tail of the worklist region [WOFF+total, WOFF+CAP).
__global__ __launch_bounds__(256) void retry_scatter(
    uint32_t* __restrict__ ws, uint32_t FOFF, uint32_t BOFF,
    uint32_t WOFF, uint32_t CAP)
{
  __shared__ uint32_t cnts[4];
  uint32_t totalA = ws[0]; if (totalA > CAP) totalA = CAP;
  uint32_t spare = CAP - totalA;
  uint32_t j = blockIdx.x * 256u + threadIdx.x;
  uint32_t fb = 0;
  if (j < CAP) fb = ((const uint8_t*)ws)[(size_t)FOFF*4u + j];
  uint64_t b = __ballot(fb != 0u);
  int lane = threadIdx.x & 63, w = threadIdx.x >> 6;
  if (lane == 0) cnts[w] = (uint32_t)__popcll(b);
  __syncthreads();
  uint32_t wb = ws[BOFF + blockIdx.x];
  for (int w2 = 0; w2 < w; ++w2) wb += cnts[w2];
  if (fb != 0u) {
    uint32_t rank = (uint32_t)__popcll(b & ((1ull << lane) - 1ull));
    uint32_t idx = wb + rank;
    if (idx < spare) ws[WOFF + totalA + idx] = (j << 2) | fb;
  }
}

// ---- Phase G3: resume failed gammas from the advanced chain key.
__global__ __launch_bounds__(256) void retry_exec(
    uint32_t* __restrict__ ws, int N, uint32_t WOFF, uint32_t CAP, uint32_t RMAX)
{
  uint32_t totalA = ws[0]; if (totalA > CAP) totalA = CAP;
  uint32_t spare = CAP - totalA;
  uint32_t rtot = ws[1];
  if (rtot > spare) rtot = spare;
  if (rtot > RMAX) rtot = RMAX;
  uint32_t i = blockIdx.x * 256u + threadIdx.x;
  if (i >= rtot) return;
  uint32_t rec = ws[WOFF + totalA + i];
  uint32_t j = rec >> 2, fb = rec & 3u;
  uint32_t ent = ws[WOFF + j];
  uint32_t t = ent >> 23, e = (ent >> 6) & 0x1FFFFu, pv = ent & 0x3Fu;
  const uint32_t* __restrict__ p = ws + KEYOFF + (size_t)t * WSTRIDE;
  float alpha = (float)pv;
  float* jarr = (float*)(ws + JOFF);
  size_t jb = (size_t)t * (size_t)(2*N) + (size_t)(2u*e);
  if (fb & 1u) {
    U2 gk = tf(p[2], p[3], 0u, 2u*e);
    U2 K  = tf(gk.a, gk.b, 0u, 0u);
    K = tf(K.a, K.b, 0u, 0u);            // skip rejected attempt 1
    float s = gamma_fromK(K.a, K.b, alpha) / 10.0f;
    jarr[jb] = __fadd_rn(jarr[jb], s);
  }
  if (fb & 2u) {
    U2 gk = tf(p[2], p[3], 0u, 2u*e + 1u);
    U2 K  = tf(gk.a, gk.b, 0u, 0u);
    K = tf(K.a, K.b, 0u, 0u);
    float s = gamma_fromK(K.a, K.b, alpha);
    jarr[jb + 1] = __fadd_rn(jarr[jb + 1], s);
  }
}

// ---- tier-1 fused jump (writes combined noise+jump) ----
__global__ __launch_bounds__(256) void jump_kernel(
    uint32_t* __restrict__ ws, const float* __restrict__ diffp, int N, int steps)
{
  int e = blockIdx.x * 256 + threadIdx.x;
  int t = blockIdx.y;
  if (e >= N) return;
  const uint32_t* __restrict__ p = ws + KEYOFF + (size_t)t * WSTRIDE;
  const uint32_t ue = (uint32_t)e;
  const float coef = __fmul_rn(diffp[0], SQDTF);
  float lp = 0.0f; int k = 0;
  #pragma unroll 1
  for (int i = 0; i < NPK; ++i) {
    if (!(lp > -0.8f)) break;
    k++;
    uint32_t bits = pbits(p[4 + 2*i], p[5 + 2*i], ue);
    lp = __fadd_rn(lp, xla_logf(u01(bits)));
  }
  int pois = k - 1;
  float nf0 = normal_from_bits(pbits(p[0], p[1], 2u*ue));
  float nf1 = normal_from_bits(pbits(p[0], p[1], 2u*ue + 1u));
  float j0 = __fmul_rn(coef, nf0), j1 = __fmul_rn(coef, nf1);
  if (pois > 0) {
    uint32_t kg0 = p[2], kg1 = p[3];
    float alpha = (float)pois;
    U2 gk0 = tf(kg0, kg1, 0u, 2u*ue);
    j0 = __fadd_rn(j0, gamma_one(gk0.a, gk0.b, alpha) / 10.0f);
    U2 gk1 = tf(kg0, kg1, 0u, 2u*ue + 1u);
    j1 = __fadd_rn(j1, gamma_one(gk1.a, gk1.b, alpha));
  }
  float* jarr = (float*)(ws + JOFF);
  size_t jbase = (size_t)t * (size_t)(2*N) + (size_t)(2*e);
  jarr[jbase] = j0; jarr[jbase + 1] = j1;
}

// ---- integrator: 8 lanes per element (round-15, known-good).
#define IBLK 256
__global__ __launch_bounds__(IBLK) void integrate_kernel(
    const float* __restrict__ z0, const float* __restrict__ W1,
    const float* __restrict__ b1, const float* __restrict__ W2,
    const float* __restrict__ b2, const float* __restrict__ diffp,
    const uint32_t* __restrict__ ws, float* __restrict__ out,
    int N, int steps)
{
  __shared__ float smem[322];
  for (int k = threadIdx.x; k < 322; k += IBLK) {
    float v;
    if (k < 128)      v = W1[k];
    else if (k < 192) v = b1[k - 128];
    else if (k < 320) v = W2[k - 192];
    else              v = b2[k - 320];
    smem[k] = v;
  }
  __syncthreads();
  const float* sW1 = smem;
  const float* sb1 = smem + 128;
  const float* sW2 = smem + 192;
  const float* sb2 = smem + 320;

  int tid = blockIdx.x * IBLK + threadIdx.x;
  const int e = tid >> 3;
  const int s = tid & 7;
  if (e >= N) return;

  const int hb = s << 3;
  float2 xv = *(const float2*)&z0[2*e];
  float x0 = xv.x, x1 = xv.y;
  const size_t orow = (size_t)(steps + 1) * 2u;
  float* op = out + (size_t)e * orow;
  if (s == 0) *(float2*)&op[0] = xv;

  const float DTf  = 0.02f;
  const float2* __restrict__ jarr2 = (const float2*)(ws + JOFF);
  const float b20 = sb2[0], b21 = sb2[1];

  for (int t = 0; t < steps; ++t) {
    float2 S = jarr2[(size_t)t * (size_t)N + (size_t)e];

    v2f xv0 = (v2f){x0, x0};
    v2f xv1 = (v2f){x1, x1};
    v2f accA = (v2f){0.0f, 0.0f};
    v2f accB = (v2f){0.0f, 0.0f};
    #pragma unroll
    for (int j = 0; j < 2; ++j) {
      {
        int h = hb + 2*j;
        v2f pre = f2fma(xv0, *(const v2f*)&sW1[h],
                  f2fma(xv1, *(const v2f*)&sW1[64 + h], *(const v2f*)&sb1[h]));
        float hv0 = fast_tanh(pre.x), hv1 = fast_tanh(pre.y);
        accA = f2fma((v2f){hv0, hv0}, *(const v2f*)&sW2[2*h], accA);
        accA = f2fma((v2f){hv1, hv1}, *(const v2f*)&sW2[2*h + 2], accA);
      }
      {
        int h = hb + 4 + 2*j;
        v2f pre = f2fma(xv0, *(const v2f*)&sW1[h],
                  f2fma(xv1, *(const v2f*)&sW1[64 + h], *(const v2f*)&sb1[h]));
        float hv0 = fast_tanh(pre.x), hv1 = fast_tanh(pre.y);
        accB = f2fma((v2f){hv0, hv0}, *(const v2f*)&sW2[2*h], accB);
        accB = f2fma((v2f){hv1, hv1}, *(const v2f*)&sW2[2*h + 2], accB);
      }
    }
    v2f acc = accA + accB;
    float q0 = acc.x, q1 = acc.y;
    q0 = q0 + __shfl_xor(q0, 1, 64);
    q1 = q1 + __shfl_xor(q1, 1, 64);
    q0 = q0 + __shfl_xor(q0, 2, 64);
    q1 = q1 + __shfl_xor(q1, 2, 64);
    q0 = q0 + __shfl_xor(q0, 4, 64);
    q1 = q1 + __shfl_xor(q1, 4, 64);
    float dr0 = b20 + q0;
    float dr1 = b21 + q1;

    x0 = __fadd_rn(__fadd_rn(x0, __fmul_rn(dr0, DTf)), S.x);
    x1 = __fadd_rn(__fadd_rn(x1, __fmul_rn(dr1, DTf)), S.y);
    if (s == 0) {
      float2 o; o.x = x0; o.y = x1;
      *(float2*)&op[(size_t)(t + 1) * 2u] = o;
    }
  }
}

// ---- tier-2: monolithic fallback (round-4, known-good, original rounding) ----
__global__ __launch_bounds__(64) void sim_fallback_kernel(
    const float* __restrict__ z0, const float* __restrict__ W1,
    const float* __restrict__ b1, const float* __restrict__ W2,
    const float* __restrict__ b2, const float* __restrict__ diffp,
    const uint32_t* __restrict__ ws, float* __restrict__ out,
    int N, int steps)
{
  __shared__ float smem[322];
  for (int k = threadIdx.x; k < 322; k += 64) {
    float v;
    if (k < 128)      v = W1[k];
    else if (k < 192) v = b1[k - 128];
    else if (k < 320) v = W2[k - 192];
    else              v = b2[k - 320];
    smem[k] = v;
  }
  __syncthreads();
  const float* sW1 = smem;
  const float* sb1 = smem + 128;
  const float* sW2 = smem + 192;
  const float* sb2 = smem + 320;

  int tid = blockIdx.x * 64 + threadIdx.x;
  if (tid >= 2 * N) return;
  const int e = tid >> 1;
  const int f = tid & 1;
  const uint32_t ue   = (uint32_t)e;
  const uint32_t utid = (uint32_t)tid;

  float x = z0[tid];
  const size_t obase = (size_t)e * (size_t)(steps + 1) * 2u + (size_t)f;
  out[obase] = x;

  const float DTf  = 0.02f;
  const float coef = __fmul_rn(diffp[0], SQDTF);
  const int   hbase = f << 5;

  for (int t = 0; t < steps; ++t) {
    const uint32_t* __restrict__ p = ws + KEYOFF + (size_t)t * WSTRIDE;
    int pois;
    {
      float lp = 0.0f;
      pois = NPK - 1;
      #pragma unroll 1
      for (int m = 0; m < NPK/2; ++m) {
        int i0 = 2*m + f;
        uint32_t bits = pbits(p[4 + 2*i0], p[5 + 2*i0], ue);
        float lmine = xla_logf(u01(bits));
        float lother = __shfl_xor(lmine, 1, 64);
        float la = (f == 0) ? lmine : lother;
        float lb = (f == 0) ? lother : lmine;
        float s1 = __fadd_rn(lp, la);
        float s2 = __fadd_rn(s1, lb);
        if (!(s1 > -0.8f)) { pois = 2*m; break; }
        if (!(s2 > -0.8f)) { pois = 2*m + 1; break; }
        lp = s2;
      }
    }
    float nf = normal_from_bits(pbits(p[0], p[1], utid));
    float jump = 0.0f;
    if (pois > 0) {
      U2 gk = tf(p[2], p[3], 0u, utid);
      float s = gamma_one(gk.a, gk.b, (float)pois);
      jump = (f == 0) ? (s / 10.0f) : s;
    }
    float xo = __shfl_xor(x, 1, 64);
    float xf0 = (f == 0) ? x : xo;
    float xf1 = (f == 0) ? xo : x;
    float p0 = 0.0f, p1 = 0.0f;
    #pragma unroll
    for (int i = 0; i < 32; ++i) {
      int h = hbase + i;
      float hv = fast_tanh(fmaf(xf0, sW1[h], fmaf(xf1, sW1[64 + h], sb1[h])));
      p0 = fmaf(hv, sW2[2*h],     p0);
      p1 = fmaf(hv, sW2[2*h + 1], p1);
    }
    float q0 = p0 + __shfl_xor(p0, 1, 64);
    float q1 = p1 + __shfl_xor(p1, 1, 64);
    float dr = sb2[f] + ((f == 0) ? q0 : q1);
    x = __fadd_rn(__fadd_rn(__fadd_rn(x, __fmul_rn(dr, DTf)),
                            __fmul_rn(coef, nf)), jump);
    out[obase + (size_t)(t + 1) * 2u] = x;
  }
}

extern "C" void kernel_launch(void* const* d_in, const int* in_sizes, int n_in,
                              void* d_out, int out_size, void* d_ws, size_t ws_size,
                              hipStream_t stream) {
  const float* z0  = (const float*)d_in[0];
  const float* W1  = (const float*)d_in[1];
  const float* b1  = (const float*)d_in[2];
  const float* W2  = (const float*)d_in[3];
  const float* b2  = (const float*)d_in[4];
  const float* dif = (const float*)d_in[5];
  int N = in_sizes[0] / 2;
  int steps = out_size / (N * 2) - 1;
  uint32_t* ws = (uint32_t*)d_ws;
  int total = 2 * N;

  hipLaunchKernelGGL(setup_kernel, dim3((steps + 255) / 256), dim3(256), 0, stream,
                     ws, steps);

  // workspace layout (u32 units): [0]=totalA [1]=retryTotal | KEYOFF keys |
  // JOFF jarr | POFF pois-bytes (reused as gamma fail flags) | COFF counts |
  // BOFF bases | WOFF worklist (pois retry records early; spare tail = gamma
  // retry list later)
  size_t JSZ = (size_t)2 * (size_t)N * (size_t)steps;
  size_t PSZ = ((size_t)N * (size_t)steps + 3u) / 4u;
  int    NBX = (N + 255) / 256;
  size_t NB  = (size_t)NBX * (size_t)steps;
  size_t CAP = ((size_t)N * (size_t)steps * 11u) / 16u;
  size_t POFFs = (size_t)JOFF + JSZ;
  size_t COFFs = POFFs + PSZ;
  size_t BOFFs = COFFs + NB;
  size_t WOFFs = BOFFs + NB;
  size_t need0 = (WOFFs + CAP) * 4u;
  size_t need1 = ((size_t)JOFF + JSZ) * 4u;
  int    NB2 = (int)((CAP + 255u) / 256u);
  bool pk = (N < (1 << 17)) && (steps < (1 << 9)) && (steps <= 314) &&
            ((size_t)NB2 <= NB) && (NB * (2u*RSLOT) <= CAP) &&
            (WOFFs + CAP < 0xFFFFFFFFull);

  int total8 = 8 * N;

  if (pk && ws_size >= need0) {
    hipLaunchKernelGGL(pois1_kernel, dim3(NBX, steps), dim3(256), 0, stream,
                       ws, dif, N, steps, (uint32_t)POFFs, (uint32_t)COFFs,
                       (uint32_t)WOFFs);
    hipLaunchKernelGGL(pois_retry_kernel, dim3(NBX, steps), dim3(64), 0, stream,
                       ws, N, (uint32_t)POFFs, (uint32_t)COFFs, (uint32_t)WOFFs);
    hipLaunchKernelGGL(prefix_kernel, dim3(1), dim3(256), 0, stream,
                       ws, (uint32_t)COFFs, (uint32_t)BOFFs, (int)NB, 0, 1);
    hipLaunchKernelGGL(scatter_kernel, dim3(NBX, steps), dim3(256), 0, stream,
                       ws, N, steps, (uint32_t)POFFs, (uint32_t)BOFFs,
                       (uint32_t)WOFFs, (uint32_t)CAP);
    hipLaunchKernelGGL(gamma_pass1, dim3(NB2), dim3(256), 0, stream,
                       ws, N, (uint32_t)WOFFs, (uint32_t)CAP,
                       (uint32_t)POFFs, (uint32_t)COFFs);
    hipLaunchKernelGGL(prefix_kernel, dim3(1), dim3(256), 0, stream,
                       ws, (uint32_t)COFFs, (uint32_t)BOFFs, NB2, 1, 0);
    hipLaunchKernelGGL(retry_scatter, dim3(NB2), dim3(256), 0, stream,
                       ws, (uint32_t)POFFs, (uint32_t)BOFFs,
                       (uint32_t)WOFFs, (uint32_t)CAP);
    uint32_t RMAX = (uint32_t)(((CAP / 4u) + 255u) / 256u) * 256u;
    hipLaunchKernelGGL(retry_exec, dim3(RMAX / 256u), dim3(256), 0, stream,
                       ws, N, (uint32_t)WOFFs, (uint32_t)CAP, RMAX);
    hipLaunchKernelGGL(integrate_kernel, dim3((total8 + IBLK - 1) / IBLK), dim3(IBLK),
                       0, stream, z0, W1, b1, W2, b2, dif, ws, (float*)d_out, N, steps);
  } else if (steps <= 314 && ws_size >= need1) {
    hipLaunchKernelGGL(jump_kernel, dim3((N + 255) / 256, steps), dim3(256), 0, stream,
                       ws, dif, N, steps);
    hipLaunchKernelGGL(integrate_kernel, dim3((total8 + IBLK - 1) / IBLK), dim3(IBLK),
                       0, stream, z0, W1, b1, W2, b2, dif, ws, (float*)d_out, N, steps);
  } else {
    hipLaunchKernelGGL(sim_fallback_kernel, dim3((total + 63) / 64), dim3(64), 0, stream,
                       z0, W1, b1, W2, b2, dif, ws, (float*)d_out, N, steps);
  }
}

// Round 17
// 1465.706 us; speedup vs baseline: 1.1573x; 1.1573x over previous
//
#include <hip/hip_runtime.h>
#include <cstdint>
#include <cmath>

#define DEVINL __device__ __forceinline__

struct U2 { uint32_t a, b; };
typedef float v2f __attribute__((ext_vector_type(2)));

DEVINL uint32_t rotl32(uint32_t x, uint32_t r){ return (x << r) | (x >> (32u - r)); }

// Threefry-2x32, 20 rounds (Random123 / JAX-compatible)
DEVINL U2 tf(uint32_t k0, uint32_t k1, uint32_t x0, uint32_t x1){
  const uint32_t k2 = k0 ^ k1 ^ 0x1BD11BDAu;
  x0 += k0; x1 += k1;
#define TFR(r) { x0 += x1; x1 = rotl32(x1,(r)); x1 ^= x0; }
  TFR(13) TFR(15) TFR(26) TFR(6)  x0 += k1; x1 += k2 + 1u;
  TFR(17) TFR(29) TFR(16) TFR(24) x0 += k2; x1 += k0 + 2u;
  TFR(13) TFR(15) TFR(26) TFR(6)  x0 += k0; x1 += k1 + 3u;
  TFR(17) TFR(29) TFR(16) TFR(24) x0 += k1; x1 += k2 + 4u;
  TFR(13) TFR(15) TFR(26) TFR(6)  x0 += k2; x1 += k0 + 5u;
#undef TFR
  U2 r; r.a = x0; r.b = x1; return r;
}

// partitionable random_bits (32-bit): one tf per element, XOR both words
DEVINL uint32_t pbits(uint32_t k0, uint32_t k1, uint32_t idx){
  U2 r = tf(k0, k1, 0u, idx);
  return r.a ^ r.b;
}

// JAX uniform bits -> [0,1): bitcast((bits>>9)|0x3F800000) - 1
DEVINL float u01(uint32_t bits){
  return __uint_as_float((bits >> 9) | 0x3F800000u) - 1.0f;
}

// XLA:CPU vectorized log (Cephes), FMA-contracted Horner
DEVINL float xla_logf(float xin){
  float xf = fmaxf(__uint_as_float(0x00800000u), xin);   // flush denorm/zero up
  uint32_t ib = __float_as_uint(xf);
  float e = (float)((int)(ib >> 23) - 126);
  float x = __uint_as_float((ib & 0x807fffffu) | 0x3f000000u);  // [0.5,1)
  bool m = x < 0.707106781186547524f;
  float t = m ? x : 0.0f;
  x = __fsub_rn(x, 1.0f);
  if (m) e = __fsub_rn(e, 1.0f);
  x = __fadd_rn(x, t);
  float z = __fmul_rn(x, x);
  float y = 7.0376836292e-2f;
  y = fmaf(y, x, -1.1514610310e-1f);
  y = fmaf(y, x,  1.1676998740e-1f);
  y = fmaf(y, x, -1.2420140846e-1f);
  y = fmaf(y, x,  1.4249322787e-1f);
  y = fmaf(y, x, -1.6668057665e-1f);
  y = fmaf(y, x,  2.0000714765e-1f);
  y = fmaf(y, x, -2.4999993993e-1f);
  y = fmaf(y, x,  3.3333331174e-1f);
  y = __fmul_rn(y, x);
  y = __fmul_rn(y, z);
  y = fmaf(e, -2.12194440e-4f, y);
  y = fmaf(z, -0.5f, y);
  x = __fadd_rn(x, y);
  x = fmaf(e, 0.693359375f, x);
  if (xin == 0.0f) x = __uint_as_float(0xff800000u);  // -inf
  return x;
}

// XLA EmitLog1p: |x|<1e-4 -> x*(1 + (-0.5)*x), else log(1+x)
DEVINL float xla_log1pf(float v){
  float av = fabsf(v);
  if (av < 1e-4f) return __fmul_rn(__fadd_rn(__fmul_rn(-0.5f, v), 1.0f), v);
  return xla_logf(__fadd_rn(v, 1.0f));
}

// XLA ErfInv32 (Giles), strict mul/add
DEVINL float erfinv32(float x){
  float xx = __fmul_rn(x, x);
  float w = -xla_log1pf(-xx);
  float p;
  if (w < 5.0f){
    float ww = __fsub_rn(w, 2.5f);
    p = 2.81022636e-08f;
    p = __fadd_rn( 3.43273939e-07f, __fmul_rn(p, ww));
    p = __fadd_rn(-3.5233877e-06f,  __fmul_rn(p, ww));
    p = __fadd_rn(-4.39150654e-06f, __fmul_rn(p, ww));
    p = __fadd_rn( 0.00021858087f,  __fmul_rn(p, ww));
    p = __fadd_rn(-0.00125372503f,  __fmul_rn(p, ww));
    p = __fadd_rn(-0.00417768164f,  __fmul_rn(p, ww));
    p = __fadd_rn( 0.246640727f,    __fmul_rn(p, ww));
    p = __fadd_rn( 1.50140941f,     __fmul_rn(p, ww));
  } else {
    float ww = __fsub_rn(sqrtf(w), 3.0f);
    p = -0.000200214257f;
    p = __fadd_rn( 0.000100950558f, __fmul_rn(p, ww));
    p = __fadd_rn( 0.00134934322f,  __fmul_rn(p, ww));
    p = __fadd_rn(-0.00367342844f,  __fmul_rn(p, ww));
    p = __fadd_rn( 0.00573950773f,  __fmul_rn(p, ww));
    p = __fadd_rn(-0.0076224613f,   __fmul_rn(p, ww));
    p = __fadd_rn( 0.00943887047f,  __fmul_rn(p, ww));
    p = __fadd_rn( 1.00167406f,     __fmul_rn(p, ww));
    p = __fadd_rn( 2.83297682f,     __fmul_rn(p, ww));
  }
  return __fmul_rn(p, x);
}

#define SQRT2F (__uint_as_float(0x3FB504F3u))   /* f32(sqrt(2)) */
#define NLOF   (__uint_as_float(0xBF7FFFFFu))   /* nextafterf(-1,0) */
#define SQDTF  ((float)0.14142135623730951)     /* f32(sqrt(0.02)) */

DEVINL float normal_from_bits(uint32_t bits){
  float ff = u01(bits);
  float u = __fadd_rn(__fmul_rn(ff, 2.0f), NLOF);
  u = fmaxf(NLOF, u);
  return __fmul_rn(SQRT2F, erfinv32(u));
}

// fast tanh for the smooth drift path (no PRNG decision depends on it)
DEVINL float fast_tanh(float x){
  float ax = fabsf(x);
  float e = __expf(-2.0f * ax);
  float r = (1.0f - e) * __builtin_amdgcn_rcpf(1.0f + e);
  return __builtin_copysignf(r, x);
}

// packed 2xf32 fma (v_pk_fma_f32 on gfx950); per-component IEEE fma
DEVINL v2f f2fma(v2f a, v2f b, v2f c){ return __builtin_elementwise_fma(a, b, c); }

// One rejection-sampling ATTEMPT (incl. inner v>0 loop). Returns accept;
// decision/value sequence byte-identical to one iteration of jax _gamma_one.
DEVINL bool gamma_attempt(uint32_t K0, uint32_t K1, float d, float c, float& out){
  U2 xk = tf(K0, K1, 0u, 1u);
  U2 Uk = tf(K0, K1, 0u, 2u);
  float xx, v;
  for (;;) {
    U2 sub = tf(xk.a, xk.b, 0u, 1u);
    xx = normal_from_bits(pbits(sub.a, sub.b, 0u));
    v = __fadd_rn(1.0f, __fmul_rn(xx, c));
    if (v > 0.0f) break;
    xk = tf(xk.a, xk.b, 0u, 0u);
  }
  float X = __fmul_rn(xx, xx);
  float V = __fmul_rn(__fmul_rn(v, v), v);
  float U = u01(pbits(Uk.a, Uk.b, 0u));
  float sq = __fsub_rn(1.0f, __fmul_rn(0.0331f, __fmul_rn(X, X)));
  if (U < sq) { out = __fmul_rn(d, V); return true; }
  float lnU = xla_logf(U);
  float lnV = xla_logf(V);
  float rhs = __fadd_rn(__fmul_rn(X, 0.5f),
                        __fmul_rn(d, __fadd_rn(__fsub_rn(1.0f, V), lnV)));
  if (lnU < rhs) { out = __fmul_rn(d, V); return true; }
  return false;
}

// Full loop starting from a given chain key K (used by retry, K pre-advanced).
DEVINL float gamma_fromK(uint32_t K0, uint32_t K1, float alpha){
  const float d = __fsub_rn(alpha, (1.0f/3.0f));
  const float c = (1.0f/3.0f) / sqrtf(d);
  for (;;) {
    float s;
    if (gamma_attempt(K0, K1, d, c, s)) return s;
    U2 K = tf(K0, K1, 0u, 0u);
    K0 = K.a; K1 = K.b;
  }
}

// jax _gamma_one from the per-element key (tier-1/fallback use).
DEVINL float gamma_one(uint32_t gk0, uint32_t gk1, float alpha){
  U2 K = tf(gk0, gk1, 0u, 0u);   // key,subkey=split; u_boost unused for alpha>=1
  return gamma_fromK(K.a, K.b, alpha);
}

#define NPK 24
#define WSTRIDE (4 + 2*NPK)
#define KEYOFF 8
#define JOFF   16384
#define RSLOT 128          /* retry records per pois block (mean 49, 12-sigma) */

// Per-step keys: kn, kg, Poisson subkey chain.
__global__ void setup_kernel(uint32_t* __restrict__ ws, int steps){
  int t = blockIdx.x * blockDim.x + threadIdx.x;
  if (t >= steps) return;
  U2 kt = tf(0u, 42u, 0u, (uint32_t)t);
  U2 kp = tf(kt.a, kt.b, 0u, 0u);
  U2 kn = tf(kt.a, kt.b, 0u, 1u);
  U2 kg = tf(kt.a, kt.b, 0u, 2u);
  uint32_t* p = ws + KEYOFF + (size_t)t * WSTRIDE;
  p[0] = kn.a; p[1] = kn.b;
  p[2] = kg.a; p[3] = kg.b;
  uint32_t r0 = kp.a, r1 = kp.b;
  for (int i = 0; i < NPK; ++i) {
    U2 sub = tf(r0, r1, 0u, 1u);
    U2 rn  = tf(r0, r1, 0u, 0u);
    p[4 + 2*i] = sub.a; p[5 + 2*i] = sub.b;
    r0 = rn.a; r1 = rn.b;
  }
}

// ---- Phase A1: Poisson first TWO draws (81% finish), straight-line uniform.
// Noise terms into jarr; pois byte 0/1 (retries overwritten later); retry
// record = element id (ONE u32; lp2 recomputed in retry) into per-block
// region of the worklist area; counts packed gamma | retry<<16 into COFF.
__global__ __launch_bounds__(256) void pois1_kernel(
    uint32_t* __restrict__ ws, const float* __restrict__ diffp,
    int N, int steps, uint32_t POFF, uint32_t COFF, uint32_t WOFF)
{
  __shared__ uint32_t gcnts[4], rcnts[4];
  int e = blockIdx.x * 256 + threadIdx.x;
  int t = blockIdx.y;
  bool act = e < N;
  const uint32_t* __restrict__ p = ws + KEYOFF + (size_t)t * WSTRIDE;
  const float coef = __fmul_rn(diffp[0], SQDTF);

  bool g = false, retry = false;
  if (act) {
    const uint32_t ue = (uint32_t)e;
    // draws 1 & 2 unconditionally (element-indexed streams; unused = discarded)
    float l1 = xla_logf(u01(pbits(p[4], p[5], ue)));
    float l2 = xla_logf(u01(pbits(p[6], p[7], ue)));
    float lpa = __fadd_rn(0.0f, l1);
    g = (lpa > -0.8f);                     // pois >= 1
    float lp2 = __fadd_rn(lpa, l2);
    retry = g && (lp2 > -0.8f);            // pois >= 2
    // noise terms
    float nf0 = normal_from_bits(pbits(p[0], p[1], 2u*ue));
    float nf1 = normal_from_bits(pbits(p[0], p[1], 2u*ue + 1u));
    float* jarr = (float*)(ws + JOFF);
    size_t jb = (size_t)t * (size_t)(2*N) + 2u*ue;
    jarr[jb]     = __fmul_rn(coef, nf0);
    jarr[jb + 1] = __fmul_rn(coef, nf1);
    ((uint8_t*)ws)[(size_t)POFF*4u + (size_t)t*(size_t)N + (size_t)e] =
        (uint8_t)(g ? 1 : 0);              // retries overwritten by retry pass
  }

  uint64_t gb = __ballot(g);
  uint64_t rb = __ballot(retry);
  int lane = threadIdx.x & 63, w = threadIdx.x >> 6;
  if (lane == 0) { gcnts[w] = (uint32_t)__popcll(gb); rcnts[w] = (uint32_t)__popcll(rb); }
  __syncthreads();
  uint32_t bid = (uint32_t)blockIdx.y * gridDim.x + blockIdx.x;
  // rank-scatter retry element ids into block-private region
  if (retry) {
    uint32_t base = 0;
    for (int w2 = 0; w2 < w; ++w2) base += rcnts[w2];
    uint32_t rank = base + (uint32_t)__popcll(rb & ((1ull << lane) - 1ull));
    if (rank < RSLOT)
      ws[WOFF + (size_t)bid * RSLOT + rank] = (uint32_t)e;
  }
  if (threadIdx.x == 0) {
    uint32_t gc = gcnts[0] + gcnts[1] + gcnts[2] + gcnts[3];
    uint32_t rc = rcnts[0] + rcnts[1] + rcnts[2] + rcnts[3];
    ws[COFF + bid] = gc | (rc << 16);
  }
}

// ---- Phase A2: continue Knuth chains for pois>=2 elements (19%).
// Recomputes l1,l2 (bit-identical) then continues from draw index k=2.
__global__ __launch_bounds__(64) void pois_retry_kernel(
    uint32_t* __restrict__ ws, int N, uint32_t POFF, uint32_t COFF, uint32_t WOFF)
{
  uint32_t bid = (uint32_t)blockIdx.y * gridDim.x + blockIdx.x;
  uint32_t cnt = ws[COFF + bid] >> 16;
  if (cnt > RSLOT) cnt = RSLOT;
  const int t = blockIdx.y;
  const uint32_t* __restrict__ p = ws + KEYOFF + (size_t)t * WSTRIDE;
  uint8_t* pb = (uint8_t*)ws + (size_t)POFF * 4u + (size_t)t * (size_t)N;
  const uint32_t* base = ws + WOFF + (size_t)bid * RSLOT;
  for (uint32_t r = threadIdx.x; r < cnt; r += 64) {
    uint32_t e = base[r];
    float l1 = xla_logf(u01(pbits(p[4], p[5], e)));
    float l2 = xla_logf(u01(pbits(p[6], p[7], e)));
    float lp = __fadd_rn(__fadd_rn(0.0f, l1), l2);
    int k = 2;
    #pragma unroll 1
    while (lp > -0.8f && k < NPK) {
      uint32_t bits = pbits(p[4 + 2*k], p[5 + 2*k], e);
      lp = __fadd_rn(lp, xla_logf(u01(bits)));
      k++;
    }
    int pois = (lp > -0.8f) ? (NPK - 1) : (k - 1);
    pb[e] = (uint8_t)pois;
  }
}

// ---- prefix over NB block counts (optionally masking low 16 bits);
// total -> ws[outIdx].
__global__ __launch_bounds__(256) void prefix_kernel(
    uint32_t* __restrict__ ws, uint32_t COFF, uint32_t BOFF, int NB,
    int outIdx, int mask16)
{
  __shared__ uint32_t ssum[256];
  int i = threadIdx.x;
  int chunk = (NB + 255) >> 8;
  int lo = i * chunk, hi = lo + chunk; if (hi > NB) hi = NB;
  uint32_t s = 0;
  for (int j = lo; j < hi; ++j) {
    uint32_t v = ws[COFF + j];
    s += mask16 ? (v & 0xFFFFu) : v;
  }
  ssum[i] = s;
  __syncthreads();
  if (i == 0) {
    uint32_t run = 0;
    for (int k = 0; k < 256; ++k) { uint32_t c = ssum[k]; ssum[k] = run; run += c; }
    ws[outIdx] = run;
  }
  __syncthreads();
  uint32_t base = ssum[i];
  for (int j = lo; j < hi; ++j) {
    ws[BOFF + j] = base;
    uint32_t v = ws[COFF + j];
    base += mask16 ? (v & 0xFFFFu) : v;
  }
}

// ---- Phase S: deterministic rank-scatter of (t,e,pois) entries.
__global__ __launch_bounds__(256) void scatter_kernel(
    uint32_t* __restrict__ ws, int N, int steps,
    uint32_t POFF, uint32_t BOFF, uint32_t WOFF, uint32_t CAP)
{
  __shared__ uint32_t cnts[4];
  int e = blockIdx.x * 256 + threadIdx.x;
  int t = blockIdx.y;
  bool act = e < N;
  uint32_t pv = 0;
  if (act) pv = ((const uint8_t*)ws)[(size_t)POFF*4u + (size_t)t*(size_t)N + (size_t)e];
  uint64_t b = __ballot(pv > 0);
  int lane = threadIdx.x & 63, w = threadIdx.x >> 6;
  if (lane == 0) cnts[w] = (uint32_t)__popcll(b);
  __syncthreads();
  uint32_t bid = (uint32_t)blockIdx.y * gridDim.x + blockIdx.x;
  uint32_t wb = ws[BOFF + bid];
  for (int w2 = 0; w2 < w; ++w2) wb += cnts[w2];
  if (pv > 0) {
    uint32_t rank = (uint32_t)__popcll(b & ((1ull << lane) - 1ull));
    uint32_t idx = wb + rank;
    if (idx < CAP)
      ws[WOFF + idx] = ((uint32_t)t << 23) | ((uint32_t)e << 6) | pv;
  }
}

// ---- Phase G1: FIRST ATTEMPT only per gamma (96% accept, no outer replay).
__global__ __launch_bounds__(256) void gamma_pass1(
    uint32_t* __restrict__ ws, int N,
    uint32_t WOFF, uint32_t CAP, uint32_t FOFF, uint32_t COFF)
{
  __shared__ uint32_t cnts[4];
  uint32_t total = ws[0]; if (total > CAP) total = CAP;
  uint32_t j = blockIdx.x * 256u + threadIdx.x;
  uint32_t fb = 0;
  if (j < total) {
    uint32_t ent = ws[WOFF + j];
    uint32_t t = ent >> 23, e = (ent >> 6) & 0x1FFFFu, pv = ent & 0x3Fu;
    const uint32_t* __restrict__ p = ws + KEYOFF + (size_t)t * WSTRIDE;
    uint32_t kg0 = p[2], kg1 = p[3];
    float alpha = (float)pv;
    const float d = __fsub_rn(alpha, (1.0f/3.0f));
    const float c = (1.0f/3.0f) / sqrtf(d);
    float add0 = 0.0f, add1 = 0.0f;
    {
      U2 gk = tf(kg0, kg1, 0u, 2u*e);
      U2 K  = tf(gk.a, gk.b, 0u, 0u);
      float s;
      if (gamma_attempt(K.a, K.b, d, c, s)) add0 = s / 10.0f; else fb |= 1u;
    }
    {
      U2 gk = tf(kg0, kg1, 0u, 2u*e + 1u);
      U2 K  = tf(gk.a, gk.b, 0u, 0u);
      float s;
      if (gamma_attempt(K.a, K.b, d, c, s)) add1 = s; else fb |= 2u;
    }
    float* jarr = (float*)(ws + JOFF);
    float2* slot = (float2*)&jarr[(size_t)t * (size_t)(2*N) + (size_t)(2u*e)];
    float2 v = *slot;
    v.x = __fadd_rn(v.x, add0);
    v.y = __fadd_rn(v.y, add1);
    *slot = v;
  }
  if (j < CAP) ((uint8_t*)ws)[(size_t)FOFF*4u + j] = (uint8_t)fb;
  uint64_t b = __ballot(fb != 0u);
  int lane = threadIdx.x & 63, w = threadIdx.x >> 6;
  if (lane == 0) cnts[w] = (uint32_t)__popcll(b);
  __syncthreads();
  if (threadIdx.x == 0)
    ws[COFF + blockIdx.x] = cnts[0] + cnts[1] + cnts[2] + cnts[3];
}

// ---- Phase G2: rank-scatter failed entries (packed (j<<2)|fb) into the
// spare tail of the worklist region [WOFF+total, WOFF+CAP).
__global__ __launch_bounds__(256) void retry_scatter(
    uint32_t* __restrict__ ws, uint32_t FOFF, uint32_t BOFF,
    uint32_t WOFF, uint32_t CAP)
{
  __shared__ uint32_t cnts[4];
  uint32_t totalA = ws[0]; if (totalA > CAP) totalA = CAP;
  uint32_t spare = CAP - totalA;
  uint32_t j = blockIdx.x * 256u + threadIdx.x;
  uint32_t fb = 0;
  if (j < CAP) fb = ((const uint8_t*)ws)[(size_t)FOFF*4u + j];
  uint64_t b = __ballot(fb != 0u);
  int lane = threadIdx.x & 63, w = threadIdx.x >> 6;
  if (lane == 0) cnts[w] = (uint32_t)__popcll(b);
  __syncthreads();
  uint32_t wb = ws[BOFF + blockIdx.x];
  for (int w2 = 0; w2 < w; ++w2) wb += cnts[w2];
  if (fb != 0u) {
    uint32_t rank = (uint32_t)__popcll(b & ((1ull << lane) - 1ull));
    uint32_t idx = wb + rank;
    if (idx < spare) ws[WOFF + totalA + idx] = (j << 2) | fb;
  }
}

// ---- Phase G3: resume failed gammas from the advanced chain key.
__global__ __launch_bounds__(256) void retry_exec(
    uint32_t* __restrict__ ws, int N, uint32_t WOFF, uint32_t CAP, uint32_t RMAX)
{
  uint32_t totalA = ws[0]; if (totalA > CAP) totalA = CAP;
  uint32_t spare = CAP - totalA;
  uint32_t rtot = ws[1];
  if (rtot > spare) rtot = spare;
  if (rtot > RMAX) rtot = RMAX;
  uint32_t i = blockIdx.x * 256u + threadIdx.x;
  if (i >= rtot) return;
  uint32_t rec = ws[WOFF + totalA + i];
  uint32_t j = rec >> 2, fb = rec & 3u;
  uint32_t ent = ws[WOFF + j];
  uint32_t t = ent >> 23, e = (ent >> 6) & 0x1FFFFu, pv = ent & 0x3Fu;
  const uint32_t* __restrict__ p = ws + KEYOFF + (size_t)t * WSTRIDE;
  float alpha = (float)pv;
  float* jarr = (float*)(ws + JOFF);
  size_t jb = (size_t)t * (size_t)(2*N) + (size_t)(2u*e);
  if (fb & 1u) {
    U2 gk = tf(p[2], p[3], 0u, 2u*e);
    U2 K  = tf(gk.a, gk.b, 0u, 0u);
    K = tf(K.a, K.b, 0u, 0u);            // skip rejected attempt 1
    float s = gamma_fromK(K.a, K.b, alpha) / 10.0f;
    jarr[jb] = __fadd_rn(jarr[jb], s);
  }
  if (fb & 2u) {
    U2 gk = tf(p[2], p[3], 0u, 2u*e + 1u);
    U2 K  = tf(gk.a, gk.b, 0u, 0u);
    K = tf(K.a, K.b, 0u, 0u);
    float s = gamma_fromK(K.a, K.b, alpha);
    jarr[jb + 1] = __fadd_rn(jarr[jb + 1], s);
  }
}

// ---- tier-1 fused jump (writes combined noise+jump) ----
__global__ __launch_bounds__(256) void jump_kernel(
    uint32_t* __restrict__ ws, const float* __restrict__ diffp, int N, int steps)
{
  int e = blockIdx.x * 256 + threadIdx.x;
  int t = blockIdx.y;
  if (e >= N) return;
  const uint32_t* __restrict__ p = ws + KEYOFF + (size_t)t * WSTRIDE;
  const uint32_t ue = (uint32_t)e;
  const float coef = __fmul_rn(diffp[0], SQDTF);
  float lp = 0.0f; int k = 0;
  #pragma unroll 1
  for (int i = 0; i < NPK; ++i) {
    if (!(lp > -0.8f)) break;
    k++;
    uint32_t bits = pbits(p[4 + 2*i], p[5 + 2*i], ue);
    lp = __fadd_rn(lp, xla_logf(u01(bits)));
  }
  int pois = k - 1;
  float nf0 = normal_from_bits(pbits(p[0], p[1], 2u*ue));
  float nf1 = normal_from_bits(pbits(p[0], p[1], 2u*ue + 1u));
  float j0 = __fmul_rn(coef, nf0), j1 = __fmul_rn(coef, nf1);
  if (pois > 0) {
    uint32_t kg0 = p[2], kg1 = p[3];
    float alpha = (float)pois;
    U2 gk0 = tf(kg0, kg1, 0u, 2u*ue);
    j0 = __fadd_rn(j0, gamma_one(gk0.a, gk0.b, alpha) / 10.0f);
    U2 gk1 = tf(kg0, kg1, 0u, 2u*ue + 1u);
    j1 = __fadd_rn(j1, gamma_one(gk1.a, gk1.b, alpha));
  }
  float* jarr = (float*)(ws + JOFF);
  size_t jbase = (size_t)t * (size_t)(2*N) + (size_t)(2*e);
  jarr[jbase] = j0; jarr[jbase + 1] = j1;
}

// ---- integrator: 8 lanes per element (round-15, known-good).
#define IBLK 256
__global__ __launch_bounds__(IBLK) void integrate_kernel(
    const float* __restrict__ z0, const float* __restrict__ W1,
    const float* __restrict__ b1, const float* __restrict__ W2,
    const float* __restrict__ b2, const float* __restrict__ diffp,
    const uint32_t* __restrict__ ws, float* __restrict__ out,
    int N, int steps)
{
  __shared__ float smem[322];
  for (int k = threadIdx.x; k < 322; k += IBLK) {
    float v;
    if (k < 128)      v = W1[k];
    else if (k < 192) v = b1[k - 128];
    else if (k < 320) v = W2[k - 192];
    else              v = b2[k - 320];
    smem[k] = v;
  }
  __syncthreads();
  const float* sW1 = smem;
  const float* sb1 = smem + 128;
  const float* sW2 = smem + 192;
  const float* sb2 = smem + 320;

  int tid = blockIdx.x * IBLK + threadIdx.x;
  const int e = tid >> 3;
  const int s = tid & 7;
  if (e >= N) return;

  const int hb = s << 3;
  float2 xv = *(const float2*)&z0[2*e];
  float x0 = xv.x, x1 = xv.y;
  const size_t orow = (size_t)(steps + 1) * 2u;
  float* op = out + (size_t)e * orow;
  if (s == 0) *(float2*)&op[0] = xv;

  const float DTf  = 0.02f;
  const float2* __restrict__ jarr2 = (const float2*)(ws + JOFF);
  const float b20 = sb2[0], b21 = sb2[1];

  for (int t = 0; t < steps; ++t) {
    float2 S = jarr2[(size_t)t * (size_t)N + (size_t)e];

    v2f xv0 = (v2f){x0, x0};
    v2f xv1 = (v2f){x1, x1};
    v2f accA = (v2f){0.0f, 0.0f};
    v2f accB = (v2f){0.0f, 0.0f};
    #pragma unroll
    for (int j = 0; j < 2; ++j) {
      {
        int h = hb + 2*j;
        v2f pre = f2fma(xv0, *(const v2f*)&sW1[h],
                  f2fma(xv1, *(const v2f*)&sW1[64 + h], *(const v2f*)&sb1[h]));
        float hv0 = fast_tanh(pre.x), hv1 = fast_tanh(pre.y);
        accA = f2fma((v2f){hv0, hv0}, *(const v2f*)&sW2[2*h], accA);
        accA = f2fma((v2f){hv1, hv1}, *(const v2f*)&sW2[2*h + 2], accA);
      }
      {
        int h = hb + 4 + 2*j;
        v2f pre = f2fma(xv0, *(const v2f*)&sW1[h],
                  f2fma(xv1, *(const v2f*)&sW1[64 + h], *(const v2f*)&sb1[h]));
        float hv0 = fast_tanh(pre.x), hv1 = fast_tanh(pre.y);
        accB = f2fma((v2f){hv0, hv0}, *(const v2f*)&sW2[2*h], accB);
        accB = f2fma((v2f){hv1, hv1}, *(const v2f*)&sW2[2*h + 2], accB);
      }
    }
    v2f acc = accA + accB;
    float q0 = acc.x, q1 = acc.y;
    q0 = q0 + __shfl_xor(q0, 1, 64);
    q1 = q1 + __shfl_xor(q1, 1, 64);
    q0 = q0 + __shfl_xor(q0, 2, 64);
    q1 = q1 + __shfl_xor(q1, 2, 64);
    q0 = q0 + __shfl_xor(q0, 4, 64);
    q1 = q1 + __shfl_xor(q1, 4, 64);
    float dr0 = b20 + q0;
    float dr1 = b21 + q1;

    x0 = __fadd_rn(__fadd_rn(x0, __fmul_rn(dr0, DTf)), S.x);
    x1 = __fadd_rn(__fadd_rn(x1, __fmul_rn(dr1, DTf)), S.y);
    if (s == 0) {
      float2 o; o.x = x0; o.y = x1;
      *(float2*)&op[(size_t)(t + 1) * 2u] = o;
    }
  }
}

// ---- tier-2: monolithic fallback (round-4, known-good, original rounding) ----
__global__ __launch_bounds__(64) void sim_fallback_kernel(
    const float* __restrict__ z0, const float* __restrict__ W1,
    const float* __restrict__ b1, const float* __restrict__ W2,
    const float* __restrict__ b2, const float* __restrict__ diffp,
    const uint32_t* __restrict__ ws, float* __restrict__ out,
    int N, int steps)
{
  __shared__ float smem[322];
  for (int k = threadIdx.x; k < 322; k += 64) {
    float v;
    if (k < 128)      v = W1[k];
    else if (k < 192) v = b1[k - 128];
    else if (k < 320) v = W2[k - 192];
    else              v = b2[k - 320];
    smem[k] = v;
  }
  __syncthreads();
  const float* sW1 = smem;
  const float* sb1 = smem + 128;
  const float* sW2 = smem + 192;
  const float* sb2 = smem + 320;

  int tid = blockIdx.x * 64 + threadIdx.x;
  if (tid >= 2 * N) return;
  const int e = tid >> 1;
  const int f = tid & 1;
  const uint32_t ue   = (uint32_t)e;
  const uint32_t utid = (uint32_t)tid;

  float x = z0[tid];
  const size_t obase = (size_t)e * (size_t)(steps + 1) * 2u + (size_t)f;
  out[obase] = x;

  const float DTf  = 0.02f;
  const float coef = __fmul_rn(diffp[0], SQDTF);
  const int   hbase = f << 5;

  for (int t = 0; t < steps; ++t) {
    const uint32_t* __restrict__ p = ws + KEYOFF + (size_t)t * WSTRIDE;
    int pois;
    {
      float lp = 0.0f;
      pois = NPK - 1;
      #pragma unroll 1
      for (int m = 0; m < NPK/2; ++m) {
        int i0 = 2*m + f;
        uint32_t bits = pbits(p[4 + 2*i0], p[5 + 2*i0], ue);
        float lmine = xla_logf(u01(bits));
        float lother = __shfl_xor(lmine, 1, 64);
        float la = (f == 0) ? lmine : lother;
        float lb = (f == 0) ? lother : lmine;
        float s1 = __fadd_rn(lp, la);
        float s2 = __fadd_rn(s1, lb);
        if (!(s1 > -0.8f)) { pois = 2*m; break; }
        if (!(s2 > -0.8f)) { pois = 2*m + 1; break; }
        lp = s2;
      }
    }
    float nf = normal_from_bits(pbits(p[0], p[1], utid));
    float jump = 0.0f;
    if (pois > 0) {
      U2 gk = tf(p[2], p[3], 0u, utid);
      float s = gamma_one(gk.a, gk.b, (float)pois);
      jump = (f == 0) ? (s / 10.0f) : s;
    }
    float xo = __shfl_xor(x, 1, 64);
    float xf0 = (f == 0) ? x : xo;
    float xf1 = (f == 0) ? xo : x;
    float p0 = 0.0f, p1 = 0.0f;
    #pragma unroll
    for (int i = 0; i < 32; ++i) {
      int h = hbase + i;
      float hv = fast_tanh(fmaf(xf0, sW1[h], fmaf(xf1, sW1[64 + h], sb1[h])));
      p0 = fmaf(hv, sW2[2*h],     p0);
      p1 = fmaf(hv, sW2[2*h + 1], p1);
    }
    float q0 = p0 + __shfl_xor(p0, 1, 64);
    float q1 = p1 + __shfl_xor(p1, 1, 64);
    float dr = sb2[f] + ((f == 0) ? q0 : q1);
    x = __fadd_rn(__fadd_rn(__fadd_rn(x, __fmul_rn(dr, DTf)),
                            __fmul_rn(coef, nf)), jump);
    out[obase + (size_t)(t + 1) * 2u] = x;
  }
}

extern "C" void kernel_launch(void* const* d_in, const int* in_sizes, int n_in,
                              void* d_out, int out_size, void* d_ws, size_t ws_size,
                              hipStream_t stream) {
  const float* z0  = (const float*)d_in[0];
  const float* W1  = (const float*)d_in[1];
  const float* b1  = (const float*)d_in[2];
  const float* W2  = (const float*)d_in[3];
  const float* b2  = (const float*)d_in[4];
  const float* dif = (const float*)d_in[5];
  int N = in_sizes[0] / 2;
  int steps = out_size / (N * 2) - 1;
  uint32_t* ws = (uint32_t*)d_ws;
  int total = 2 * N;

  hipLaunchKernelGGL(setup_kernel, dim3((steps + 255) / 256), dim3(256), 0, stream,
                     ws, steps);

  // workspace layout (u32 units): [0]=totalA [1]=retryTotal | KEYOFF keys |
  // JOFF jarr | POFF pois-bytes (reused as gamma fail flags) | COFF counts |
  // BOFF bases | WOFF worklist (pois retry ids early; spare tail = gamma
  // retry list later)
  size_t JSZ = (size_t)2 * (size_t)N * (size_t)steps;
  size_t PSZ = ((size_t)N * (size_t)steps + 3u) / 4u;
  int    NBX = (N + 255) / 256;
  size_t NB  = (size_t)NBX * (size_t)steps;
  size_t CAP = ((size_t)N * (size_t)steps * 11u) / 16u;
  size_t POFFs = (size_t)JOFF + JSZ;
  size_t COFFs = POFFs + PSZ;
  size_t BOFFs = COFFs + NB;
  size_t WOFFs = BOFFs + NB;
  size_t need0 = (WOFFs + CAP) * 4u;
  size_t need1 = ((size_t)JOFF + JSZ) * 4u;
  int    NB2 = (int)((CAP + 255u) / 256u);
  bool pk = (N < (1 << 17)) && (steps < (1 << 9)) && (steps <= 314) &&
            ((size_t)NB2 <= NB) && (NB * (size_t)RSLOT <= CAP) &&
            (WOFFs + CAP < 0xFFFFFFFFull);

  int total8 = 8 * N;

  if (pk && ws_size >= need0) {
    hipLaunchKernelGGL(pois1_kernel, dim3(NBX, steps), dim3(256), 0, stream,
                       ws, dif, N, steps, (uint32_t)POFFs, (uint32_t)COFFs,
                       (uint32_t)WOFFs);
    hipLaunchKernelGGL(pois_retry_kernel, dim3(NBX, steps), dim3(64), 0, stream,
                       ws, N, (uint32_t)POFFs, (uint32_t)COFFs, (uint32_t)WOFFs);
    hipLaunchKernelGGL(prefix_kernel, dim3(1), dim3(256), 0, stream,
                       ws, (uint32_t)COFFs, (uint32_t)BOFFs, (int)NB, 0, 1);
    hipLaunchKernelGGL(scatter_kernel, dim3(NBX, steps), dim3(256), 0, stream,
                       ws, N, steps, (uint32_t)POFFs, (uint32_t)BOFFs,
                       (uint32_t)WOFFs, (uint32_t)CAP);
    hipLaunchKernelGGL(gamma_pass1, dim3(NB2), dim3(256), 0, stream,
                       ws, N, (uint32_t)WOFFs, (uint32_t)CAP,
                       (uint32_t)POFFs, (uint32_t)COFFs);
    hipLaunchKernelGGL(prefix_kernel, dim3(1), dim3(256), 0, stream,
                       ws, (uint32_t)COFFs, (uint32_t)BOFFs, NB2, 1, 0);
    hipLaunchKernelGGL(retry_scatter, dim3(NB2), dim3(256), 0, stream,
                       ws, (uint32_t)POFFs, (uint32_t)BOFFs,
                       (uint32_t)WOFFs, (uint32_t)CAP);
    uint32_t RMAX = (uint32_t)(((CAP / 4u) + 255u) / 256u) * 256u;
    hipLaunchKernelGGL(retry_exec, dim3(RMAX / 256u), dim3(256), 0, stream,
                       ws, N, (uint32_t)WOFFs, (uint32_t)CAP, RMAX);
    hipLaunchKernelGGL(integrate_kernel, dim3((total8 + IBLK - 1) / IBLK), dim3(IBLK),
                       0, stream, z0, W1, b1, W2, b2, dif, ws, (float*)d_out, N, steps);
  } else if (steps <= 314 && ws_size >= need1) {
    hipLaunchKernelGGL(jump_kernel, dim3((N + 255) / 256, steps), dim3(256), 0, stream,
                       ws, dif, N, steps);
    hipLaunchKernelGGL(integrate_kernel, dim3((total8 + IBLK - 1) / IBLK), dim3(IBLK),
                       0, stream, z0, W1, b1, W2, b2, dif, ws, (float*)d_out, N, steps);
  } else {
    hipLaunchKernelGGL(sim_fallback_kernel, dim3((total + 63) / 64), dim3(64), 0, stream,
                       z0, W1, b1, W2, b2, dif, ws, (float*)d_out, N, steps);
  }
}